// Round 11
// baseline (5064.841 us; speedup 1.0000x reference)
//
#include <hip/hip_runtime.h>

#define SS 2048
#define HH 64

typedef _Float16 h2v __attribute__((ext_vector_type(2)));
typedef unsigned int uint;

__device__ __forceinline__ float fdot2f(uint w, uint x, float c) {
#if __has_builtin(__builtin_amdgcn_fdot2)
    return __builtin_amdgcn_fdot2(__builtin_bit_cast(h2v, w),
                                  __builtin_bit_cast(h2v, x), c, false);
#else
    h2v a = __builtin_bit_cast(h2v, w), bb = __builtin_bit_cast(h2v, x);
    return fmaf((float)a[0], (float)bb[0], fmaf((float)a[1], (float)bb[1], c));
#endif
}
__device__ __forceinline__ uint pack2(float a, float b) {
    h2v v = {(_Float16)a, (_Float16)b};
    return __builtin_bit_cast(uint, v);
}
__device__ __forceinline__ unsigned short f16bits(float a) {
    return __builtin_bit_cast(unsigned short, (_Float16)a);
}
__device__ __forceinline__ float fast_tanh(float x) {
    float ax = fabsf(x);
    float e = __expf(-2.0f * ax);
    float r = (1.0f - e) * __builtin_amdgcn_rcpf(1.0f + e);
    return copysignf(r, x);
}
__device__ __forceinline__ float fast_sigmoid(float x) {
    return __builtin_amdgcn_rcpf(1.0f + __expf(-x));
}

__global__ __launch_bounds__(256)
__attribute__((amdgpu_waves_per_eu(1, 1)))
void pgjanet_kernel(
    const float* __restrict__ x,     // [B,S,2]
    const float* __restrict__ h0,    // [1,B,H]
    const float* __restrict__ Wa,    // [65,64]
    const float* __restrict__ ba,
    const float* __restrict__ Wp1,
    const float* __restrict__ bp1,
    const float* __restrict__ Wp2,
    const float* __restrict__ bp2,
    const float* __restrict__ Wz,    // [128,64]
    const float* __restrict__ bz,
    const float* __restrict__ Wh,    // [128,64]
    const float* __restrict__ bh,
    const float* __restrict__ Wout,  // [64,2]
    const float* __restrict__ bout,
    float* __restrict__ out)         // [B,S,2]
{
    const int b   = blockIdx.x;
    const int tid = threadIdx.x;     // 0..255
    const int j   = tid & 63;
    const int wid = tid >> 6;        // 0..3
    const int zoff = wid * 8;        // zh pair-slice base

    __shared__ float2 xs2[SS];                            // 16 KB
    __shared__ __align__(16) unsigned short hpk[4][64];   // per-wave h (f16)
    __shared__ __align__(16) unsigned short upk[4][64];   // per-wave u (f16)
    __shared__ float aLm[64], p1Lm[64], p2Lm[64];
    __shared__ float zhp[4][64];
    __shared__ float hhLm[64];
    __shared__ float pBm[4][64];
    __shared__ float hbufL[32 * 65];                      // stride 65: conflict-free
    __shared__ float WoutT[2 * 68];
    __shared__ float boutS[2];

    // ---- stage x[b] (coalesced) + Wout^T ----
    {
        const float2* xb = (const float2*)(x + (size_t)b * SS * 2);
        #pragma unroll
        for (int it = 0; it < SS / 256; ++it)
            xs2[tid + it * 256] = xb[tid + it * 256];
    }
    if (tid < 64) {
        WoutT[0 * 68 + tid] = Wout[tid * 2 + 0];
        WoutT[1 * 68 + tid] = Wout[tid * 2 + 1];
    }
    if (tid < 2) boutS[tid] = bout[tid];

    // ---- per-wave weight slices (56 packed f16 pairs per lane) ----
    const float* mainW;
    float w0r = 0.f, bAr = 0.f;
    if (wid == 0)      { mainW = Wa  + HH; w0r = Wa[j];  bAr = ba[j];  }
    else if (wid == 1) { mainW = Wp1 + HH; w0r = Wp1[j]; bAr = bp1[j]; }
    else if (wid == 2) { mainW = Wp2 + HH; w0r = Wp2[j]; bAr = bp2[j]; }
    else               { mainW = Wh + 64 * HH; }          // hh (linear)

    uint wM[32], wZ8[8], wB[16];
    #pragma unroll
    for (int p = 0; p < 32; ++p)
        wM[p] = pack2(mainW[(2 * p) * HH + j], mainW[(2 * p + 1) * HH + j]);
    #pragma unroll
    for (int q = 0; q < 8; ++q) {
        const int p = zoff + q;
        wZ8[q] = pack2(Wz[(64 + 2 * p) * HH + j], Wz[(65 + 2 * p) * HH + j]);
    }
    const float* uW = (wid < 2 ? Wz : Wh) + ((wid & 1) * 32) * HH;
    #pragma unroll
    for (int p = 0; p < 16; ++p)
        wB[p] = pack2(uW[(2 * p) * HH + j], uW[(2 * p + 1) * HH + j]);

    // pin: opaque values can't be rematerialized/sunk into the loop
    #pragma unroll
    for (int k = 0; k < 32; ++k) asm volatile("" : "+v"(wM[k]));
    #pragma unroll
    for (int k = 0; k < 8; ++k)  asm volatile("" : "+v"(wZ8[k]));
    #pragma unroll
    for (int k = 0; k < 16; ++k) asm volatile("" : "+v"(wB[k]));

    const float bzR = bz[j];
    const float bhR = bh[j];

    // h carried in f32 registers (redundant in every wave); f16 copy per wave
    float hreg = h0[b * HH + j];
    hpk[wid][j] = f16bits(hreg);

    __syncthreads();

    for (int t = 0; t < SS; ++t) {
        // ---- h broadcast from OWN wave copy (R9 idiom: scalar assigns,
        //      constant indices only; NO pointer casts of locals) ----
        uint hp[32];
        {
            const uint4* hp4 = (const uint4*)hpk[wid];
            #pragma unroll
            for (int g = 0; g < 8; ++g) {
                uint4 v = hp4[g];
                hp[4*g+0] = v.x; hp[4*g+1] = v.y;
                hp[4*g+2] = v.z; hp[4*g+3] = v.w;
            }
        }

        // ---- per-step scalar input ----
        const float2 xt = xs2[t];
        const float d = xt.x * xt.x + xt.y * xt.y;
        const float inv = (d > 0.f) ? __builtin_amdgcn_rsqf(d) : 0.f;
        float scal;
        if (wid == 0)      scal = d * inv;                        // amp
        else if (wid == 1) scal = (d > 0.f) ? xt.x * inv : 1.0f;  // cos
        else if (wid == 2) scal = xt.y * inv;                     // sin
        else               scal = 0.f;

        // ---- PHASE A: main matvec (32 pairs) + zh slice (8 pairs) ----
        float c0 = 0.f, c1 = 0.f, c2 = 0.f, c3 = 0.f;
        #pragma unroll
        for (int p = 0; p < 32; p += 4) {
            c0 = fdot2f(wM[p + 0], hp[p + 0], c0);
            c1 = fdot2f(wM[p + 1], hp[p + 1], c1);
            c2 = fdot2f(wM[p + 2], hp[p + 2], c2);
            c3 = fdot2f(wM[p + 3], hp[p + 3], c3);
        }
        const float pre = (c0 + c1) + (c2 + c3) + fmaf(scal, w0r, bAr);

        float z0 = 0.f, z1 = 0.f;
        #pragma unroll
        for (int q = 0; q < 8; q += 2) {
            z0 = fdot2f(wZ8[q + 0], hp[zoff + q + 0], z0);
            z1 = fdot2f(wZ8[q + 1], hp[zoff + q + 1], z1);
        }
        zhp[wid][j] = z0 + z1;

        if (wid == 0)      aLm[j]  = fast_tanh(pre);
        else if (wid == 1) p1Lm[j] = fast_tanh(pre);
        else if (wid == 2) p2Lm[j] = fast_tanh(pre);
        else               hhLm[j] = pre;
        __syncthreads();  // bar1: gates + zhp + hh visible

        // ---- u (per-lane) + own-copy broadcast + PHASE B ----
        {
            const float av  = aLm[j];
            const float p1v = p1Lm[j];
            const float p2v = p2Lm[j];
            const float uu = av * p1v * p2v * (1.f - av) * (1.f - p1v) * (1.f - p2v);
            upk[wid][j] = f16bits(uu);

            // own-wave broadcast reads of the 16-pair slice (same idiom)
            uint up[16];
            {
                const uint4* up4 = (const uint4*)(upk[wid] + (wid & 1) * 32);
                #pragma unroll
                for (int g = 0; g < 4; ++g) {
                    uint4 v = up4[g];
                    up[4*g+0] = v.x; up[4*g+1] = v.y;
                    up[4*g+2] = v.z; up[4*g+3] = v.w;
                }
            }

            // fold partials while u-reads are in flight
            float fold;
            if (wid == 0)      fold = zhp[0][j] + zhp[1][j];
            else if (wid == 1) fold = zhp[2][j] + zhp[3][j];
            else if (wid == 2) fold = hhLm[j];
            else               fold = 0.f;

            float b0 = 0.f, b1 = 0.f, b2 = 0.f, b3 = 0.f;
            #pragma unroll
            for (int p = 0; p < 16; p += 4) {
                b0 = fdot2f(wB[p + 0], up[p + 0], b0);
                b1 = fdot2f(wB[p + 1], up[p + 1], b1);
                b2 = fdot2f(wB[p + 2], up[p + 2], b2);
                b3 = fdot2f(wB[p + 3], up[p + 3], b3);
            }
            pBm[wid][j] = (b0 + b1) + (b2 + b3) + fold;
        }
        __syncthreads();  // bar2: pB visible

        // ---- COMBINE (all waves redundantly; h stays f32 in registers) ----
        {
            const float zpre = pBm[0][j] + pBm[1][j] + bzR;
            const float hpre = pBm[2][j] + pBm[3][j] + bhR;
            const float zz = fast_sigmoid(zpre);
            const float hc = fast_tanh(hpre);
            hreg = fmaf(zz, hreg - hc, hc);
            hpk[wid][j] = f16bits(hreg);          // own copy for next step
            if (wid == 3) hbufL[(t & 31) * 65 + j] = hreg;
        }
        // no bar3: hpk/upk own-wave; aLm/zhp/hhLm: B(t)-read < bar2(t) <
        // A(t+1)-write; pBm: C(t)-read < bar1(t+1) < B(t+1)-write; hbufL
        // wave-3 only. All hazards covered by bar1/bar2 of adjacent steps.

        // ---- output flush every 32 steps (wave 3; banks (r+k)%32 distinct) ----
        if ((t & 31) == 31 && wid == 3) {
            const int r = j >> 1, o = j & 1;
            float acc = 0.f;
            #pragma unroll
            for (int k = 0; k < 64; ++k)
                acc += hbufL[r * 65 + k] * WoutT[o * 68 + k];
            out[((size_t)b * SS + (t - 31 + r)) * 2 + o] = acc + boutS[o];
        }
    }
}

extern "C" void kernel_launch(void* const* d_in, const int* in_sizes, int n_in,
                              void* d_out, int out_size, void* d_ws, size_t ws_size,
                              hipStream_t stream) {
    const float* x    = (const float*)d_in[0];
    const float* h0   = (const float*)d_in[1];
    const float* Wa   = (const float*)d_in[2];
    const float* ba   = (const float*)d_in[3];
    const float* Wp1  = (const float*)d_in[4];
    const float* bp1  = (const float*)d_in[5];
    const float* Wp2  = (const float*)d_in[6];
    const float* bp2  = (const float*)d_in[7];
    const float* Wz   = (const float*)d_in[8];
    const float* bz   = (const float*)d_in[9];
    const float* Wh   = (const float*)d_in[10];
    const float* bh   = (const float*)d_in[11];
    const float* Wout = (const float*)d_in[12];
    const float* bout = (const float*)d_in[13];
    float* out = (float*)d_out;

    pgjanet_kernel<<<256, 256, 0, stream>>>(x, h0, Wa, ba, Wp1, bp1, Wp2, bp2,
                                            Wz, bz, Wh, bh, Wout, bout, out);
}

// Round 12
// 1866.038 us; speedup vs baseline: 2.7142x; 2.7142x over previous
//
#include <hip/hip_runtime.h>

#define SS 2048
#define HH 64

typedef _Float16 h2v __attribute__((ext_vector_type(2)));
typedef unsigned int uint;

__device__ __forceinline__ float fdot2f(uint w, uint x, float c) {
#if __has_builtin(__builtin_amdgcn_fdot2)
    return __builtin_amdgcn_fdot2(__builtin_bit_cast(h2v, w),
                                  __builtin_bit_cast(h2v, x), c, false);
#else
    h2v a = __builtin_bit_cast(h2v, w), bb = __builtin_bit_cast(h2v, x);
    return fmaf((float)a[0], (float)bb[0], fmaf((float)a[1], (float)bb[1], c));
#endif
}
__device__ __forceinline__ uint pack2(float a, float b) {
    h2v v = {(_Float16)a, (_Float16)b};
    return __builtin_bit_cast(uint, v);
}
__device__ __forceinline__ unsigned short f16bits(float a) {
    return __builtin_bit_cast(unsigned short, (_Float16)a);
}
__device__ __forceinline__ float fast_tanh(float x) {
    float ax = fabsf(x);
    float e = __expf(-2.0f * ax);
    float r = (1.0f - e) * __builtin_amdgcn_rcpf(1.0f + e);
    return copysignf(r, x);
}
__device__ __forceinline__ float fast_sigmoid(float x) {
    return __builtin_amdgcn_rcpf(1.0f + __expf(-x));
}

__global__ __launch_bounds__(64)
__attribute__((amdgpu_waves_per_eu(1, 1)))
void pgjanet_kernel(
    const float* __restrict__ x,     // [B,S,2]
    const float* __restrict__ h0,    // [1,B,H]
    const float* __restrict__ Wa,    // [65,64]
    const float* __restrict__ ba,
    const float* __restrict__ Wp1,
    const float* __restrict__ bp1,
    const float* __restrict__ Wp2,
    const float* __restrict__ bp2,
    const float* __restrict__ Wz,    // [128,64]
    const float* __restrict__ bz,
    const float* __restrict__ Wh,    // [128,64]
    const float* __restrict__ bh,
    const float* __restrict__ Wout,  // [64,2]
    const float* __restrict__ bout,
    float* __restrict__ out)         // [B,S,2]
{
    const int b = blockIdx.x;
    const int j = threadIdx.x;       // 0..63, one wave per block

    __shared__ float2 xs2[SS];                         // 16 KB
    __shared__ __align__(16) unsigned short hpk[HH];   // h as f16
    __shared__ __align__(16) unsigned short upk[HH];   // u as f16
    __shared__ float hbufL[32 * 65];                   // stash, conflict-free
    __shared__ float WoutT[2 * 68];                    // transposed
    
    // ---- stage x[b] (coalesced), Wout^T ----
    {
        const float2* xb = (const float2*)(x + (size_t)b * SS * 2);
        #pragma unroll
        for (int it = 0; it < SS / 64; ++it)
            xs2[j + it * 64] = xb[j + it * 64];
    }
    WoutT[0 * 68 + j] = Wout[j * 2 + 0];
    WoutT[1 * 68 + j] = Wout[j * 2 + 1];
    const float bo = bout[j & 1];

    // ---- per-lane scalars ----
    const float w0a  = Wa[j],  baR  = ba[j];
    const float w0p1 = Wp1[j], bp1R = bp1[j];
    const float w0p2 = Wp2[j], bp2R = bp2[j];
    const float bzR  = bz[j],  bhR  = bh[j];

    // ---- gate weights -> arch VGPRs (96 packed pairs) ----
    uint wA[32], wP1[32], wP2[32];
    #pragma unroll
    for (int k = 0; k < 32; ++k) {
        wA[k]  = pack2(Wa [(1 + 2*k) * HH + j], Wa [(2 + 2*k) * HH + j]);
        wP1[k] = pack2(Wp1[(1 + 2*k) * HH + j], Wp1[(2 + 2*k) * HH + j]);
        wP2[k] = pack2(Wp2[(1 + 2*k) * HH + j], Wp2[(2 + 2*k) * HH + j]);
    }
    // ---- recurrent/u weights -> AGPRs (128 packed pairs) ----
    uint wZh[32], wHh[32], wZu[32], wHu[32];
    #pragma unroll
    for (int k = 0; k < 32; ++k) {
        wZh[k] = pack2(Wz[(64 + 2*k) * HH + j], Wz[(65 + 2*k) * HH + j]);
        wHh[k] = pack2(Wh[(64 + 2*k) * HH + j], Wh[(65 + 2*k) * HH + j]);
        wZu[k] = pack2(Wz[(2*k) * HH + j],      Wz[(2*k + 1) * HH + j]);
        wHu[k] = pack2(Wh[(2*k) * HH + j],      Wh[(2*k + 1) * HH + j]);
    }

    // pin homes: gates in VGPR, recurrent in AGPR (opaque -> no sinking)
    #pragma unroll
    for (int k = 0; k < 32; ++k)
        asm volatile("" : "+v"(wA[k]), "+v"(wP1[k]), "+v"(wP2[k]));
    #pragma unroll
    for (int k = 0; k < 32; ++k)
        asm volatile("" : "+a"(wZh[k]), "+a"(wHh[k]), "+a"(wZu[k]), "+a"(wHu[k]));

    // ---- initial hidden state (f32 in reg, f16 copy in LDS) ----
    float hreg = h0[b * HH + j];
    hpk[j] = f16bits(hreg);

    const uint4* hp4 = (const uint4*)hpk;   // 8 x b128 broadcast reads
    const uint4* up4 = (const uint4*)upk;

    for (int t = 0; t < SS; ++t) {
        // ---- scalar inputs (amp, cos, sin) ----
        const float2 xt = xs2[t];
        const float d = xt.x * xt.x + xt.y * xt.y;
        const float inv = (d > 0.f) ? __builtin_amdgcn_rsqf(d) : 0.f;
        const float amp = d * inv;
        const float ca  = (d > 0.f) ? xt.x * inv : 1.0f;
        const float sa  = xt.y * inv;

        // ---- PHASE A: 5 h-matvecs, groups consumed immediately ----
        float aA0 = 0.f, aA1 = 0.f, aP10 = 0.f, aP11 = 0.f;
        float aP20 = 0.f, aP21 = 0.f, aZ0 = 0.f, aZ1 = 0.f;
        float aH0 = 0.f, aH1 = 0.f;
        #pragma unroll
        for (int g = 0; g < 8; ++g) {
            const uint4 v = hp4[g];            // waits on prev step's hpk write
            aA0  = fdot2f(wA [4*g+0], v.x, aA0);
            aA1  = fdot2f(wA [4*g+1], v.y, aA1);
            aA0  = fdot2f(wA [4*g+2], v.z, aA0);
            aA1  = fdot2f(wA [4*g+3], v.w, aA1);
            aP10 = fdot2f(wP1[4*g+0], v.x, aP10);
            aP11 = fdot2f(wP1[4*g+1], v.y, aP11);
            aP10 = fdot2f(wP1[4*g+2], v.z, aP10);
            aP11 = fdot2f(wP1[4*g+3], v.w, aP11);
            aP20 = fdot2f(wP2[4*g+0], v.x, aP20);
            aP21 = fdot2f(wP2[4*g+1], v.y, aP21);
            aP20 = fdot2f(wP2[4*g+2], v.z, aP20);
            aP21 = fdot2f(wP2[4*g+3], v.w, aP21);
            aZ0  = fdot2f(wZh[4*g+0], v.x, aZ0);
            aZ1  = fdot2f(wZh[4*g+1], v.y, aZ1);
            aZ0  = fdot2f(wZh[4*g+2], v.z, aZ0);
            aZ1  = fdot2f(wZh[4*g+3], v.w, aZ1);
            aH0  = fdot2f(wHh[4*g+0], v.x, aH0);
            aH1  = fdot2f(wHh[4*g+1], v.y, aH1);
            aH0  = fdot2f(wHh[4*g+2], v.z, aH0);
            aH1  = fdot2f(wHh[4*g+3], v.w, aH1);
        }
        const float a_  = fast_tanh(aA0 + aA1 + fmaf(amp, w0a,  baR));
        const float p1_ = fast_tanh(aP10 + aP11 + fmaf(ca, w0p1, bp1R));
        const float p2_ = fast_tanh(aP20 + aP21 + fmaf(sa, w0p2, bp2R));
        const float zh  = aZ0 + aZ1;
        const float hh  = aH0 + aH1;

        const float u = a_ * p1_ * p2_ * (1.f - a_) * (1.f - p1_) * (1.f - p2_);
        upk[j] = f16bits(u);

        // ---- PHASE B: 2 u-matvecs ----
        float zU0 = 0.f, zU1 = 0.f, hU0 = 0.f, hU1 = 0.f;
        #pragma unroll
        for (int g = 0; g < 8; ++g) {
            const uint4 v = up4[g];            // waits on upk write (same wave)
            zU0 = fdot2f(wZu[4*g+0], v.x, zU0);
            zU1 = fdot2f(wZu[4*g+1], v.y, zU1);
            zU0 = fdot2f(wZu[4*g+2], v.z, zU0);
            zU1 = fdot2f(wZu[4*g+3], v.w, zU1);
            hU0 = fdot2f(wHu[4*g+0], v.x, hU0);
            hU1 = fdot2f(wHu[4*g+1], v.y, hU1);
            hU0 = fdot2f(wHu[4*g+2], v.z, hU0);
            hU1 = fdot2f(wHu[4*g+3], v.w, hU1);
        }
        const float z  = fast_sigmoid(zU0 + zU1 + zh + bzR);
        const float hc = fast_tanh(hU0 + hU1 + hh + bhR);
        hreg = fmaf(z, hreg - hc, hc);

        hpk[j] = f16bits(hreg);
        hbufL[(t & 31) * 65 + j] = hreg;

        // ---- output flush every 32 steps (within-wave, in-order) ----
        if ((t & 31) == 31) {
            const int r = j >> 1;      // row 0..31
            const int o = j & 1;       // output 0..1
            float acc = 0.f;
            #pragma unroll
            for (int k = 0; k < 64; ++k)
                acc += hbufL[r * 65 + k] * WoutT[o * 68 + k];
            out[((size_t)b * SS + (t - 31 + r)) * 2 + o] = acc + bo;
        }
    }
}

extern "C" void kernel_launch(void* const* d_in, const int* in_sizes, int n_in,
                              void* d_out, int out_size, void* d_ws, size_t ws_size,
                              hipStream_t stream) {
    const float* x    = (const float*)d_in[0];
    const float* h0   = (const float*)d_in[1];
    const float* Wa   = (const float*)d_in[2];
    const float* ba   = (const float*)d_in[3];
    const float* Wp1  = (const float*)d_in[4];
    const float* bp1  = (const float*)d_in[5];
    const float* Wp2  = (const float*)d_in[6];
    const float* bp2  = (const float*)d_in[7];
    const float* Wz   = (const float*)d_in[8];
    const float* bz   = (const float*)d_in[9];
    const float* Wh   = (const float*)d_in[10];
    const float* bh   = (const float*)d_in[11];
    const float* Wout = (const float*)d_in[12];
    const float* bout = (const float*)d_in[13];
    float* out = (float*)d_out;

    pgjanet_kernel<<<256, 64, 0, stream>>>(x, h0, Wa, ba, Wp1, bp1, Wp2, bp2,
                                           Wz, bz, Wh, bh, Wout, bout, out);
}